// Round 1
// 829.072 us; speedup vs baseline: 1.0857x; 1.0857x over previous
//
#include <hip/hip_runtime.h>
#include <hip/hip_bf16.h>

#define B_ 2
#define S_ 2048
#define HID_ 4096
#define NH_ 32
#define NKV_ 8
#define HD_ 128
#define T_ (B_*S_)

typedef __bf16 bf16;
typedef __bf16 bf16x8 __attribute__((ext_vector_type(8)));
typedef __bf16 bf16x4 __attribute__((ext_vector_type(4)));
typedef float f32x4 __attribute__((ext_vector_type(4)));

// async global->LDS, 16B per lane; LDS dest = base + lane*16 (wave-uniform base)
__device__ __forceinline__ void load_lds16(const void* g, void* l) {
  __builtin_amdgcn_global_load_lds((const __attribute__((address_space(1))) void*)g,
                                   (__attribute__((address_space(3))) void*)l, 16, 0, 0);
}

// DPP row_ror cross-lane (16-lane ring) — VALU-speed reduction, no LDS pipe
#define DPP_ROR(x, n) __int_as_float(__builtin_amdgcn_update_dpp( \
    __float_as_int(x), __float_as_int(x), 0x120 | (n), 0xf, 0xf, false))
__device__ __forceinline__ float red16_max(float x) {
  x = fmaxf(x, DPP_ROR(x, 1)); x = fmaxf(x, DPP_ROR(x, 2));
  x = fmaxf(x, DPP_ROR(x, 4)); x = fmaxf(x, DPP_ROR(x, 8));
  return x;
}
__device__ __forceinline__ float red16_sum(float x) {
  x += DPP_ROR(x, 1); x += DPP_ROR(x, 2);
  x += DPP_ROR(x, 4); x += DPP_ROR(x, 8);
  return x;
}

// ---------------- convert fp32 -> bf16 ----------------
__global__ __launch_bounds__(256) void cvt_bf16_kernel(const float* __restrict__ in,
                                                       bf16* __restrict__ out, int n4) {
  int idx = blockIdx.x * 256 + threadIdx.x;
  if (idx >= n4) return;
  float4 v = ((const float4*)in)[idx];
  bf16x4 o;
  o.x = (bf16)v.x; o.y = (bf16)v.y; o.z = (bf16)v.z; o.w = (bf16)v.w;
  ((bf16x4*)out)[idx] = o;
}

// ---------------- dequant int4(stored int32) -> bf16 ----------------
__global__ __launch_bounds__(256) void dequant_kernel(const int* __restrict__ qw,
                                                      const float* __restrict__ scale,
                                                      bf16* __restrict__ out,
                                                      int OD, int ID) {
  int idx = blockIdx.x * 256 + threadIdx.x;
  int perRow = ID >> 3;
  int total = OD * perRow;
  if (idx >= total) return;
  int o = idx / perRow;
  int ic = idx - o * perRow;
  float s = scale[o * (ID >> 7) + ((ic * 8) >> 7)];
  const int* q = qw + (size_t)o * ID + ic * 8;
  int4 q0 = *(const int4*)q;
  int4 q1 = *(const int4*)(q + 4);
  bf16x8 r;
  r[0] = (bf16)((q0.x - 8) * s);
  r[1] = (bf16)((q0.y - 8) * s);
  r[2] = (bf16)((q0.z - 8) * s);
  r[3] = (bf16)((q0.w - 8) * s);
  r[4] = (bf16)((q1.x - 8) * s);
  r[5] = (bf16)((q1.y - 8) * s);
  r[6] = (bf16)((q1.z - 8) * s);
  r[7] = (bf16)((q1.w - 8) * s);
  *(bf16x8*)(out + (size_t)o * ID + ic * 8) = r;
}

// ---------------- GEMM: C[M][N] = A[M][K] * B[N][K]^T (128-tile, kept for N=1024 shapes) ----
__global__ __launch_bounds__(256) void gemm_bt_kernel(const bf16* __restrict__ A,
                                                      const bf16* __restrict__ Bm,
                                                      void* __restrict__ Cout,
                                                      int N, int K, int c_fp32) {
  __shared__ bf16 As[8192];
  __shared__ bf16 Bs[8192];
  int tid = threadIdx.x;
  int wave = tid >> 6, lane = tid & 63, quad = lane >> 4, l16 = lane & 15;
  int m0 = blockIdx.y * 128, n0 = blockIdx.x * 128;
  int wm = (wave >> 1) * 64, wn = (wave & 1) * 64;

  int srow = lane >> 3;
  int schunk = (lane & 7) ^ (srow & 7);
  const bf16* Ab[4];
  const bf16* Bb[4];
#pragma unroll
  for (int u = 0; u < 4; u++) {
    int t = wave + 4 * u;
    Ab[u] = A  + (size_t)(m0 + 8 * t + srow) * K + schunk * 8;
    Bb[u] = Bm + (size_t)(n0 + 8 * t + srow) * K + schunk * 8;
  }

  f32x4 acc[4][4];
#pragma unroll
  for (int mt = 0; mt < 4; mt++)
#pragma unroll
    for (int nt = 0; nt < 4; nt++) acc[mt][nt] = (f32x4){0.f, 0.f, 0.f, 0.f};

  for (int k0 = 0; k0 < K; k0 += 64) {
    __syncthreads();
#pragma unroll
    for (int u = 0; u < 4; u++) {
      int t = wave + 4 * u;
      load_lds16(Ab[u] + k0, (char*)As + t * 1024);
      load_lds16(Bb[u] + k0, (char*)Bs + t * 1024);
    }
    __syncthreads();
#pragma unroll
    for (int kk = 0; kk < 2; kk++) {
      bf16x8 af[4], bfr[4];
#pragma unroll
      for (int mt = 0; mt < 4; mt++) {
        int r = wm + mt * 16 + l16;
        af[mt] = *(const bf16x8*)((const char*)As + r * 128 + (((kk * 4 + quad) ^ (r & 7)) << 4));
      }
#pragma unroll
      for (int nt = 0; nt < 4; nt++) {
        int r = wn + nt * 16 + l16;
        bfr[nt] = *(const bf16x8*)((const char*)Bs + r * 128 + (((kk * 4 + quad) ^ (r & 7)) << 4));
      }
#pragma unroll
      for (int mt = 0; mt < 4; mt++)
#pragma unroll
        for (int nt = 0; nt < 4; nt++)
          acc[mt][nt] = __builtin_amdgcn_mfma_f32_16x16x32_bf16(af[mt], bfr[nt], acc[mt][nt], 0, 0, 0);
    }
  }

#pragma unroll
  for (int mt = 0; mt < 4; mt++)
#pragma unroll
    for (int nt = 0; nt < 4; nt++)
#pragma unroll
      for (int r = 0; r < 4; r++) {
        int rr = m0 + wm + mt * 16 + quad * 4 + r;
        int cc = n0 + wn + nt * 16 + l16;
        if (c_fp32) ((float*)Cout)[(size_t)rr * N + cc] = acc[mt][nt][r];
        else        ((bf16*)Cout)[(size_t)rr * N + cc] = (bf16)acc[mt][nt][r];
      }
}

// ---------------- 128-tile GEMM + fused RoPE epilogue (kept for K projection, N=1024) ----
__global__ __launch_bounds__(256) void gemm_rope_kernel(const bf16* __restrict__ A,
                                                        const bf16* __restrict__ Bm,
                                                        bf16* __restrict__ Out,
                                                        int N, int K,
                                                        const float* __restrict__ cosT,
                                                        const float* __restrict__ sinT,
                                                        float outscale) {
  __shared__ char smem[32768];
  bf16* As = (bf16*)smem;
  bf16* Bs = (bf16*)(smem + 16384);
  float* Ex = (float*)smem;   // 256*17 floats, aliases As/Bs after main loop
  int tid = threadIdx.x;
  int wave = tid >> 6, lane = tid & 63, quad = lane >> 4, l16 = lane & 15;
  int m0 = blockIdx.y * 128, n0 = blockIdx.x * 128;
  int wm = (wave >> 1) * 64, wn = (wave & 1) * 64;

  int srow = lane >> 3;
  int schunk = (lane & 7) ^ (srow & 7);
  const bf16* Ab[4];
  const bf16* Bb[4];
#pragma unroll
  for (int u = 0; u < 4; u++) {
    int t = wave + 4 * u;
    Ab[u] = A  + (size_t)(m0 + 8 * t + srow) * K + schunk * 8;
    Bb[u] = Bm + (size_t)(n0 + 8 * t + srow) * K + schunk * 8;
  }

  f32x4 acc[4][4];
#pragma unroll
  for (int mt = 0; mt < 4; mt++)
#pragma unroll
    for (int nt = 0; nt < 4; nt++) acc[mt][nt] = (f32x4){0.f, 0.f, 0.f, 0.f};

  for (int k0 = 0; k0 < K; k0 += 64) {
    __syncthreads();
#pragma unroll
    for (int u = 0; u < 4; u++) {
      int t = wave + 4 * u;
      load_lds16(Ab[u] + k0, (char*)As + t * 1024);
      load_lds16(Bb[u] + k0, (char*)Bs + t * 1024);
    }
    __syncthreads();
#pragma unroll
    for (int kk = 0; kk < 2; kk++) {
      bf16x8 af[4], bfr[4];
#pragma unroll
      for (int mt = 0; mt < 4; mt++) {
        int r = wm + mt * 16 + l16;
        af[mt] = *(const bf16x8*)((const char*)As + r * 128 + (((kk * 4 + quad) ^ (r & 7)) << 4));
      }
#pragma unroll
      for (int nt = 0; nt < 4; nt++) {
        int r = wn + nt * 16 + l16;
        bfr[nt] = *(const bf16x8*)((const char*)Bs + r * 128 + (((kk * 4 + quad) ^ (r & 7)) << 4));
      }
#pragma unroll
      for (int mt = 0; mt < 4; mt++)
#pragma unroll
        for (int nt = 0; nt < 4; nt++)
          acc[mt][nt] = __builtin_amdgcn_mfma_f32_16x16x32_bf16(af[mt], bfr[nt], acc[mt][nt], 0, 0, 0);
    }
  }

  int myb = tid * 17;
  int pb = (tid ^ 64) * 17;    // partner: other 64-col half, same lane/regs
#pragma unroll
  for (int mt = 0; mt < 4; mt++) {
    __syncthreads();
#pragma unroll
    for (int nt = 0; nt < 4; nt++)
#pragma unroll
      for (int r = 0; r < 4; r++)
        Ex[myb + nt * 4 + r] = acc[mt][nt][r];
    __syncthreads();
    int rowb = m0 + wm + mt * 16 + quad * 4;
#pragma unroll
    for (int nt = 0; nt < 4; nt++) {
      int cc = n0 + wn + nt * 16 + l16;
      int d = cc & 127;
#pragma unroll
      for (int r = 0; r < 4; r++) {
        int row = rowb + r;
        int t = row & (S_ - 1);
        float self = acc[mt][nt][r];
        float other = Ex[pb + nt * 4 + r];
        float c = cosT[t * 128 + d], s = sinT[t * 128 + d];
        float o = (d < 64) ? (self * c - other * s) : (self * c + other * s);
        Out[(size_t)row * N + cc] = (bf16)(o * outscale);
      }
    }
  }
}

// ---------------- 256-tile 8-phase GEMM (T1+T2+T3+T4+T5), optional fused RoPE ---------
// C[M][N] = A[M][K]*B[N][K]^T. 512 thr = 8 waves (2M x 4N); per-wave C = 128x64.
// LDS 128KB: buf{0,1} x { A_k0 | A_k1 | B_k0 | B_k1 } of 16KB each ([row][64B], K-split).
// Swizzle: chunk c of row r stored at 16B-slot c ^ (r&3) ^ ((r>>2)&3)  (bank-uniform).
// Schedule per K-tile t (buf=t&1): 4 phases x {ds_read frags; stage 1 half of t+1 into
// buf^1; barrier; setprio(1); 16 MFMA; setprio(0); barrier}. Counted waits: vmcnt(4) at
// phases 1 & 3 only (2 halves always in flight); vmcnt(0) only prologue + last tile.
// Steady-state ledger: outstanding=8 loads at each checkpoint; oldest 4 = halves needed
// next -> vmcnt(4).  K-split is the phase-aligned retirement axis (kk0 dead after ph1).
template<int FUSE_ROPE, int C_FP32>
__global__ __launch_bounds__(512, 2) void gemm256_kernel(const bf16* __restrict__ A,
                                                         const bf16* __restrict__ Bm,
                                                         void* __restrict__ Cout,
                                                         int N, int K,
                                                         const float* __restrict__ cosT,
                                                         const float* __restrict__ sinT,
                                                         float outscale) {
  __shared__ char smem[131072];
  const int tid = threadIdx.x;
  const int wave = tid >> 6, lane = tid & 63, quad = lane >> 4, l16 = lane & 15;
  const int wm = (wave >> 2) * 128, wn = (wave & 3) * 64;

  // XCD-aware bijective swizzle (grid is 16x16=256, 256%8==0)
  int bid = blockIdx.y * gridDim.x + blockIdx.x;
  int cpx = (gridDim.x * gridDim.y) >> 3;
  int wgid = (bid & 7) * cpx + (bid >> 3);
  int m0 = (wgid / gridDim.x) * 256;
  int n0 = (wgid % gridDim.x) * 256;

  // staging: per half-tile 2 x global_load_lds per thread; LDS dest linear
  // (region + u*8192 + wave*1024 + lane*16)  => row = u*128 + wave*16 + (lane>>2),
  // slot = lane&3, so the pre-swizzled source chunk is c = (lane&3)^((lane>>2)&3)^quad.
  const int srow = wave * 16 + (lane >> 2);
  const int sc = (lane & 3) ^ ((lane >> 2) & 3) ^ quad;
  const bf16* aS0 = A  + (size_t)(m0 + srow) * K + sc * 8;
  const bf16* aS1 = A  + (size_t)(m0 + 128 + srow) * K + sc * 8;
  const bf16* bS0 = Bm + (size_t)(n0 + srow) * K + sc * 8;
  const bf16* bS1 = Bm + (size_t)(n0 + 128 + srow) * K + sc * 8;
  const int wl = wave * 1024;

  // frag read: addr = region + r*64 + slot*16, slot = quad ^ (r&3) ^ ((r>>2)&3);
  // since wm,wn,16*i are multiples of 16: r&3 = l16&3, (r>>2)&3 = (l16>>2)&3.
  const int rslot = ((quad ^ (l16 & 3) ^ ((l16 >> 2) & 3)) << 4);
  const int aoff = (wm + l16) * 64 + rslot;
  const int boff = (wn + l16) * 64 + rslot;

  f32x4 acc[8][4];
#pragma unroll
  for (int mt = 0; mt < 8; mt++)
#pragma unroll
    for (int nt = 0; nt < 4; nt++) acc[mt][nt] = (f32x4){0.f, 0.f, 0.f, 0.f};

  // prologue: stage all 4 halves of tile 0 into buf 0, drain once
  load_lds16(aS0,      smem +     0 + wl); load_lds16(aS1,      smem +  8192 + wl);
  load_lds16(bS0,      smem + 32768 + wl); load_lds16(bS1,      smem + 40960 + wl);
  load_lds16(aS0 + 32, smem + 16384 + wl); load_lds16(aS1 + 32, smem + 24576 + wl);
  load_lds16(bS0 + 32, smem + 49152 + wl); load_lds16(bS1 + 32, smem + 57344 + wl);
  asm volatile("s_waitcnt vmcnt(0)" ::: "memory");
  __builtin_amdgcn_s_barrier();

  const int NT = K >> 6;
  for (int t = 0; t < NT; ++t) {
    const char* base = smem + (t & 1) * 65536;
    char* nb = smem + ((t & 1) ^ 1) * 65536;
    const int off = (t + 1) << 6;      // next K-tile, in bf16 elements
    const bool more = (t + 1) < NT;
    bf16x8 afA[4], afB[4], bfr[4];

    // ---- phase 0: kk=0, rows wm..wm+63 ----
#pragma unroll
    for (int i = 0; i < 4; i++) afA[i] = *(const bf16x8*)(base + aoff + i * 1024);
#pragma unroll
    for (int i = 0; i < 4; i++) bfr[i] = *(const bf16x8*)(base + 32768 + boff + i * 1024);
    if (more) { load_lds16(aS0 + off, nb + wl); load_lds16(aS1 + off, nb + 8192 + wl); }
    __builtin_amdgcn_s_barrier();
    __builtin_amdgcn_s_setprio(1);
#pragma unroll
    for (int mt = 0; mt < 4; mt++)
#pragma unroll
      for (int nt = 0; nt < 4; nt++)
        acc[mt][nt] = __builtin_amdgcn_mfma_f32_16x16x32_bf16(afA[mt], bfr[nt], acc[mt][nt], 0, 0, 0);
    __builtin_amdgcn_s_setprio(0);
    __builtin_amdgcn_s_barrier();

    // ---- phase 1: kk=0, rows wm+64..wm+127; checkpoint: need k1 halves of tile t ----
#pragma unroll
    for (int i = 0; i < 4; i++) afB[i] = *(const bf16x8*)(base + aoff + (i + 4) * 1024);
    if (more) { load_lds16(bS0 + off, nb + 32768 + wl); load_lds16(bS1 + off, nb + 40960 + wl); }
    if (t == NT - 1) asm volatile("s_waitcnt vmcnt(0)" ::: "memory");   // epilogue drain
    else             asm volatile("s_waitcnt vmcnt(4)" ::: "memory");   // oldest 4 = k1(t)
    __builtin_amdgcn_s_barrier();
    __builtin_amdgcn_s_setprio(1);
#pragma unroll
    for (int mt = 0; mt < 4; mt++)
#pragma unroll
      for (int nt = 0; nt < 4; nt++)
        acc[mt + 4][nt] = __builtin_amdgcn_mfma_f32_16x16x32_bf16(afB[mt], bfr[nt], acc[mt + 4][nt], 0, 0, 0);
    __builtin_amdgcn_s_setprio(0);
    __builtin_amdgcn_s_barrier();

    // ---- phase 2: kk=1, rows wm..wm+63 ----
#pragma unroll
    for (int i = 0; i < 4; i++) afA[i] = *(const bf16x8*)(base + 16384 + aoff + i * 1024);
#pragma unroll
    for (int i = 0; i < 4; i++) bfr[i] = *(const bf16x8*)(base + 49152 + boff + i * 1024);
    if (more) { load_lds16(aS0 + off + 32, nb + 16384 + wl); load_lds16(aS1 + off + 32, nb + 24576 + wl); }
    __builtin_amdgcn_s_barrier();
    __builtin_amdgcn_s_setprio(1);
#pragma unroll
    for (int mt = 0; mt < 4; mt++)
#pragma unroll
      for (int nt = 0; nt < 4; nt++)
        acc[mt][nt] = __builtin_amdgcn_mfma_f32_16x16x32_bf16(afA[mt], bfr[nt], acc[mt][nt], 0, 0, 0);
    __builtin_amdgcn_s_setprio(0);
    __builtin_amdgcn_s_barrier();

    // ---- phase 3: kk=1, rows wm+64..wm+127; checkpoint: need k0 halves of tile t+1 ----
#pragma unroll
    for (int i = 0; i < 4; i++) afB[i] = *(const bf16x8*)(base + 16384 + aoff + (i + 4) * 1024);
    if (more) {
      load_lds16(bS0 + off + 32, nb + 49152 + wl); load_lds16(bS1 + off + 32, nb + 57344 + wl);
      asm volatile("s_waitcnt vmcnt(4)" ::: "memory");   // oldest 4 = k0(t+1)
    }
    __builtin_amdgcn_s_barrier();
    __builtin_amdgcn_s_setprio(1);
#pragma unroll
    for (int mt = 0; mt < 4; mt++)
#pragma unroll
      for (int nt = 0; nt < 4; nt++)
        acc[mt + 4][nt] = __builtin_amdgcn_mfma_f32_16x16x32_bf16(afB[mt], bfr[nt], acc[mt + 4][nt], 0, 0, 0);
    __builtin_amdgcn_s_setprio(0);
    __builtin_amdgcn_s_barrier();
  }

  if (FUSE_ROPE) {
    float* Ex = (float*)smem;      // 512*17 floats = 34816 B, aliases tile buffers
    int myb = tid * 17;
    int pb = (tid ^ 64) * 17;      // partner owns cc^64 (wave bit0 flips), same lane/regs
#pragma unroll
    for (int mt = 0; mt < 8; mt++) {
      __syncthreads();
#pragma unroll
      for (int nt = 0; nt < 4; nt++)
#pragma unroll
        for (int r = 0; r < 4; r++)
          Ex[myb + nt * 4 + r] = acc[mt][nt][r];
      __syncthreads();
      int rowb = m0 + wm + mt * 16 + quad * 4;
#pragma unroll
      for (int nt = 0; nt < 4; nt++) {
        int cc = n0 + wn + nt * 16 + l16;
        int d = cc & 127;
#pragma unroll
        for (int r = 0; r < 4; r++) {
          int row = rowb + r;
          int tp = row & (S_ - 1);
          float self = acc[mt][nt][r];
          float other = Ex[pb + nt * 4 + r];
          float c = cosT[tp * 128 + d], s = sinT[tp * 128 + d];
          float o = (d < 64) ? (self * c - other * s) : (self * c + other * s);
          ((bf16*)Cout)[(size_t)row * N + cc] = (bf16)(o * outscale);
        }
      }
    }
  } else {
#pragma unroll
    for (int mt = 0; mt < 8; mt++)
#pragma unroll
      for (int nt = 0; nt < 4; nt++)
#pragma unroll
        for (int r = 0; r < 4; r++) {
          int rr = m0 + wm + mt * 16 + quad * 4 + r;
          int cc = n0 + wn + nt * 16 + l16;
          if (C_FP32) ((float*)Cout)[(size_t)rr * N + cc] = acc[mt][nt][r];
          else        ((bf16*)Cout)[(size_t)rr * N + cc] = (bf16)acc[mt][nt][r];
        }
  }
}

// ---------------- fused causal GQA attention -----------------------------
// grid (8, NH, B), 512 threads = 8 waves; wave owns 16 Q rows; paired q-tiles
// (qt, 15-qt) -> uniform 34 j-iterations. K double-buffered + pipelined,
// V staged behind the QK^T/softmax phase. DPP reductions, exp2-domain softmax
// (Q pre-scaled by 1/sqrt(d)*log2(e) in rope epilogue).
__global__ __launch_bounds__(512, 4) void attn_kernel(const bf16* __restrict__ Qm,
                                                      const bf16* __restrict__ Km,
                                                      const bf16* __restrict__ VtG,
                                                      bf16* __restrict__ Cm) {
  __shared__ char sK[32768];   // 2 x 16KB: addr(key,dc16)=key*256 + ((dc^(key&7))<<4)
  __shared__ char sV[16384];   // addr(d,kc8)=d*128 + ((kc^(d&7))<<4)
  __shared__ char sP[16384];   // 8 waves x 2KB: addr(m,kc8)=m*128 + ((kc^(m&7))<<4)
  int tid = threadIdx.x;
  int wave = tid >> 6, lane = tid & 63, quad = lane >> 4, l16 = lane & 15;
  int h = blockIdx.y, b = blockIdx.z;
  int kvh = h >> 2;

  // staging pointers (qt-independent); each wave stages 2x1KB of K and of V
  const bf16* Kb[2];
  const bf16* Vb[2];
  {
    int r4 = lane >> 4, c16 = lane & 15;
    int r8 = lane >> 3, c8 = lane & 7;
#pragma unroll
    for (int u = 0; u < 2; u++) {
      int t = wave * 2 + u;
      int key = 4 * t + r4;
      int kc = c16 ^ (key & 7);
      Kb[u] = Km + (size_t)(b * S_ + key) * (NKV_ * HD_) + kvh * HD_ + kc * 8;
      int d = 8 * t + r8;
      int vc = c8 ^ (d & 7);
      Vb[u] = VtG + (size_t)(kvh * HD_ + d) * T_ + (size_t)b * S_ + vc * 8;
    }
  }

  for (int pass = 0; pass < 2; pass++) {
    int qt = pass ? ((S_ / 128 - 1) - (int)blockIdx.x) : (int)blockIdx.x;
    int q0 = qt * 128;
    int jend = q0 + 128;

    // pre-stage K tile j0=0 into buffer 0 (safe: pass N-1 readers are past
    // their last barrier before any wave gets here)
#pragma unroll
    for (int u = 0; u < 2; u++)
      load_lds16(Kb[u], sK + (wave * 2 + u) * 1024);

    // Q fragments: A[m=l16][k=quad*8+j]
    bf16x8 aQ[4];
    {
      int row = q0 + wave * 16 + l16;
      const bf16* qb = Qm + (size_t)(b * S_ + row) * (NH_ * HD_) + h * HD_;
#pragma unroll
      for (int kt = 0; kt < 4; kt++)
        aQ[kt] = *(const bf16x8*)(qb + kt * 32 + quad * 8);
    }

    float mcur[4], lcur[4];
    f32x4 O[8];
#pragma unroll
    for (int r = 0; r < 4; r++) { mcur[r] = -1e30f; lcur[r] = 0.f; }
#pragma unroll
    for (int n = 0; n < 8; n++) O[n] = (f32x4){0.f, 0.f, 0.f, 0.f};

    for (int j0 = 0; j0 < jend; j0 += 64) {
      int cur = (j0 >> 6) & 1;
      __syncthreads();   // K(cur) staged (issued one full iteration ago)
      // issue next K tile + this iteration's V tile (both land during compute)
      if (j0 + 64 < jend) {
#pragma unroll
        for (int u = 0; u < 2; u++)
          load_lds16(Kb[u] + (size_t)(j0 + 64) * (NKV_ * HD_),
                     sK + (1 - cur) * 16384 + (wave * 2 + u) * 1024);
      }
#pragma unroll
      for (int u = 0; u < 2; u++)
        load_lds16(Vb[u] + j0, sV + (wave * 2 + u) * 1024);

      // QK^T: 16 rows x 64 keys per wave
      const char* Kc = sK + cur * 16384;
      f32x4 sc[4];
#pragma unroll
      for (int nt = 0; nt < 4; nt++) sc[nt] = (f32x4){0.f, 0.f, 0.f, 0.f};
#pragma unroll
      for (int kt = 0; kt < 4; kt++) {
        bf16x8 bk[4];
#pragma unroll
        for (int nt = 0; nt < 4; nt++) {
          int key = nt * 16 + l16;
          bk[nt] = *(const bf16x8*)(Kc + key * 256 + (((kt * 4 + quad) ^ (key & 7)) << 4));
        }
#pragma unroll
        for (int nt = 0; nt < 4; nt++)
          sc[nt] = __builtin_amdgcn_mfma_f32_16x16x32_bf16(aQ[kt], bk[nt], sc[nt], 0, 0, 0);
      }

      // causal mask (wave-uniform skip for fully-visible tiles)
      int rowb = q0 + wave * 16 + quad * 4;
      if (j0 + 63 > q0 + wave * 16) {
#pragma unroll
        for (int nt = 0; nt < 4; nt++) {
          int col = j0 + nt * 16 + l16;
#pragma unroll
          for (int r = 0; r < 4; r++)
            if (col > rowb + r) sc[nt][r] = -1e9f;
        }
      }

      // online softmax (log2 domain; DPP reductions)
      float rmax[4], alpha[4], rsum[4];
#pragma unroll
      for (int r = 0; r < 4; r++) {
        float v = fmaxf(fmaxf(sc[0][r], sc[1][r]), fmaxf(sc[2][r], sc[3][r]));
        rmax[r] = red16_max(v);
        float mnew = fmaxf(mcur[r], rmax[r]);
        alpha[r] = exp2f(mcur[r] - mnew);
        mcur[r] = mnew;
      }
#pragma unroll
      for (int nt = 0; nt < 4; nt++)
#pragma unroll
        for (int r = 0; r < 4; r++)
          sc[nt][r] = exp2f(sc[nt][r] - mcur[r]);
#pragma unroll
      for (int r = 0; r < 4; r++) {
        float s = (sc[0][r] + sc[1][r]) + (sc[2][r] + sc[3][r]);
        rsum[r] = red16_sum(s);
        lcur[r] = lcur[r] * alpha[r] + rsum[r];
      }
#pragma unroll
      for (int n = 0; n < 8; n++)
#pragma unroll
        for (int r = 0; r < 4; r++) O[n][r] *= alpha[r];

      // P -> LDS (C-layout -> A-frag layout), wave-private region
      char* Pw = sP + wave * 2048;
#pragma unroll
      for (int nt = 0; nt < 4; nt++) {
        int key = nt * 16 + l16;
#pragma unroll
        for (int r = 0; r < 4; r++) {
          int m = quad * 4 + r;
          *(bf16*)(Pw + m * 128 + (((key >> 3) ^ (m & 7)) << 4) + (key & 7) * 2) =
              (bf16)sc[nt][r];
        }
      }

      __syncthreads();   // V(cur) staged (landed during QK^T+softmax); P visible intra-wave

      // ctx += P * V
#pragma unroll
      for (int kt = 0; kt < 2; kt++) {
        bf16x8 ap = *(const bf16x8*)(Pw + l16 * 128 + (((kt * 4 + quad) ^ (l16 & 7)) << 4));
#pragma unroll
        for (int nt = 0; nt < 8; nt++) {
          int d = nt * 16 + l16;
          bf16x8 bv = *(const bf16x8*)(sV + d * 128 + (((kt * 4 + quad) ^ (d & 7)) << 4));
          O[nt] = __builtin_amdgcn_mfma_f32_16x16x32_bf16(ap, bv, O[nt], 0, 0, 0);
        }
      }
    }

    // epilogue
#pragma unroll
    for (int nt = 0; nt < 8; nt++)
#pragma unroll
      for (int r = 0; r < 4; r++) {
        int row = q0 + wave * 16 + quad * 4 + r;
        Cm[(size_t)(b * S_ + row) * (NH_ * HD_) + h * HD_ + nt * 16 + l16] =
            (bf16)(O[nt][r] / lcur[r]);
      }
  }
}

extern "C" void kernel_launch(void* const* d_in, const int* in_sizes, int n_in,
                              void* d_out, int out_size, void* d_ws, size_t ws_size,
                              hipStream_t stream) {
  const float* hidden = (const float*)d_in[0];
  const float* cosT   = (const float*)d_in[1];
  const float* sinT   = (const float*)d_in[2];
  const int*   q_qw = (const int*)d_in[4];
  const float* q_sc = (const float*)d_in[5];
  const int*   k_qw = (const int*)d_in[6];
  const float* k_sc = (const float*)d_in[7];
  const int*   v_qw = (const int*)d_in[8];
  const float* v_sc = (const float*)d_in[9];
  const int*   o_qw = (const int*)d_in[10];
  const float* o_sc = (const float*)d_in[11];

  const size_t MB = 1024 * 1024;
  char* ws = (char*)d_ws;
  bf16* Xb  = (bf16*)(ws);             // 32MB  hidden bf16; later reused as ctx
  bf16* Wb  = (bf16*)(ws + 32 * MB);   // 32MB  current dequantized weight
  bf16* Qm  = (bf16*)(ws + 64 * MB);   // 32MB  [T][4096]
  bf16* Km  = (bf16*)(ws + 96 * MB);   // 8MB   [T][1024]
  bf16* VtG = (bf16*)(ws + 104 * MB);  // 8MB   [1024][T]  (V transposed)
  bf16* Cm  = Xb;

  cvt_bf16_kernel<<<(T_ * HID_ / 4 + 255) / 256, 256, 0, stream>>>(hidden, Xb, T_ * HID_ / 4);

  // Q pre-scale: 1/sqrt(128) * log2(e)  (softmax runs in exp2 domain)
  const float qscale = (float)(0.08838834764831845 * 1.4426950408889634);

  // Q projection + fused rope (256-tile 8-phase; grid 16x16 = 256 blocks = 1/CU)
  dequant_kernel<<<(4096 * 512 + 255) / 256, 256, 0, stream>>>(q_qw, q_sc, Wb, 4096, 4096);
  gemm256_kernel<1, 0><<<dim3(16, 16), 512, 0, stream>>>(Xb, Wb, Qm, 4096, 4096,
                                                         cosT, sinT, qscale);

  // K projection + fused rope (N=1024: keep 128-tile, 256 blocks)
  dequant_kernel<<<(1024 * 512 + 255) / 256, 256, 0, stream>>>(k_qw, k_sc, Wb, 1024, 4096);
  gemm_rope_kernel<<<dim3(8, 32), 256, 0, stream>>>(Xb, Wb, Km, 1024, 4096, cosT, sinT, 1.0f);

  // V projection, written TRANSPOSED: V^T[1024][T] = Wv * X^T (keep 128-tile)
  dequant_kernel<<<(1024 * 512 + 255) / 256, 256, 0, stream>>>(v_qw, v_sc, Wb, 1024, 4096);
  gemm_bt_kernel<<<dim3(32, 8), 256, 0, stream>>>(Wb, Xb, VtG, 4096, 4096, 0);

  // attention (8 waves/block, paired q-tiles; writes Cm = Xb region)
  attn_kernel<<<dim3(8, NH_, B_), 512, 0, stream>>>(Qm, Km, VtG, Cm);

  // output projection -> fp32 d_out (256-tile 8-phase)
  dequant_kernel<<<(4096 * 512 + 255) / 256, 256, 0, stream>>>(o_qw, o_sc, Wb, 4096, 4096);
  gemm256_kernel<0, 1><<<dim3(16, 16), 512, 0, stream>>>(Cm, Wb, d_out, 4096, 4096,
                                                         nullptr, nullptr, 1.0f);
}

// Round 2
// 800.438 us; speedup vs baseline: 1.1246x; 1.0358x over previous
//
#include <hip/hip_runtime.h>
#include <hip/hip_bf16.h>

#define B_ 2
#define S_ 2048
#define HID_ 4096
#define NH_ 32
#define NKV_ 8
#define HD_ 128
#define T_ (B_*S_)

typedef __bf16 bf16;
typedef __bf16 bf16x8 __attribute__((ext_vector_type(8)));
typedef __bf16 bf16x4 __attribute__((ext_vector_type(4)));
typedef float f32x4 __attribute__((ext_vector_type(4)));

// async global->LDS, 16B per lane; LDS dest = base + lane*16 (wave-uniform base)
__device__ __forceinline__ void load_lds16(const void* g, void* l) {
  __builtin_amdgcn_global_load_lds((const __attribute__((address_space(1))) void*)g,
                                   (__attribute__((address_space(3))) void*)l, 16, 0, 0);
}

// DPP row_ror cross-lane (16-lane ring) — VALU-speed reduction, no LDS pipe
#define DPP_ROR(x, n) __int_as_float(__builtin_amdgcn_update_dpp( \
    __float_as_int(x), __float_as_int(x), 0x120 | (n), 0xf, 0xf, false))
__device__ __forceinline__ float red16_max(float x) {
  x = fmaxf(x, DPP_ROR(x, 1)); x = fmaxf(x, DPP_ROR(x, 2));
  x = fmaxf(x, DPP_ROR(x, 4)); x = fmaxf(x, DPP_ROR(x, 8));
  return x;
}
__device__ __forceinline__ float red16_sum(float x) {
  x += DPP_ROR(x, 1); x += DPP_ROR(x, 2);
  x += DPP_ROR(x, 4); x += DPP_ROR(x, 8);
  return x;
}

// ---------------- convert fp32 -> bf16 ----------------
__global__ __launch_bounds__(256) void cvt_bf16_kernel(const float* __restrict__ in,
                                                       bf16* __restrict__ out, int n4) {
  int idx = blockIdx.x * 256 + threadIdx.x;
  if (idx >= n4) return;
  float4 v = ((const float4*)in)[idx];
  bf16x4 o;
  o.x = (bf16)v.x; o.y = (bf16)v.y; o.z = (bf16)v.z; o.w = (bf16)v.w;
  ((bf16x4*)out)[idx] = o;
}

// ---------------- dequant int4(stored int32) -> bf16 ----------------
__global__ __launch_bounds__(256) void dequant_kernel(const int* __restrict__ qw,
                                                      const float* __restrict__ scale,
                                                      bf16* __restrict__ out,
                                                      int OD, int ID) {
  int idx = blockIdx.x * 256 + threadIdx.x;
  int perRow = ID >> 3;
  int total = OD * perRow;
  if (idx >= total) return;
  int o = idx / perRow;
  int ic = idx - o * perRow;
  float s = scale[o * (ID >> 7) + ((ic * 8) >> 7)];
  const int* q = qw + (size_t)o * ID + ic * 8;
  int4 q0 = *(const int4*)q;
  int4 q1 = *(const int4*)(q + 4);
  bf16x8 r;
  r[0] = (bf16)((q0.x - 8) * s);
  r[1] = (bf16)((q0.y - 8) * s);
  r[2] = (bf16)((q0.z - 8) * s);
  r[3] = (bf16)((q0.w - 8) * s);
  r[4] = (bf16)((q1.x - 8) * s);
  r[5] = (bf16)((q1.y - 8) * s);
  r[6] = (bf16)((q1.z - 8) * s);
  r[7] = (bf16)((q1.w - 8) * s);
  *(bf16x8*)(out + (size_t)o * ID + ic * 8) = r;
}

// ---------------- GEMM: C[M][N] = A[M][K] * B[N][K]^T (128-tile, kept for N=1024 shapes) ----
__global__ __launch_bounds__(256) void gemm_bt_kernel(const bf16* __restrict__ A,
                                                      const bf16* __restrict__ Bm,
                                                      void* __restrict__ Cout,
                                                      int N, int K, int c_fp32) {
  __shared__ bf16 As[8192];
  __shared__ bf16 Bs[8192];
  int tid = threadIdx.x;
  int wave = tid >> 6, lane = tid & 63, quad = lane >> 4, l16 = lane & 15;
  int m0 = blockIdx.y * 128, n0 = blockIdx.x * 128;
  int wm = (wave >> 1) * 64, wn = (wave & 1) * 64;

  int srow = lane >> 3;
  int schunk = (lane & 7) ^ (srow & 7);
  const bf16* Ab[4];
  const bf16* Bb[4];
#pragma unroll
  for (int u = 0; u < 4; u++) {
    int t = wave + 4 * u;
    Ab[u] = A  + (size_t)(m0 + 8 * t + srow) * K + schunk * 8;
    Bb[u] = Bm + (size_t)(n0 + 8 * t + srow) * K + schunk * 8;
  }

  f32x4 acc[4][4];
#pragma unroll
  for (int mt = 0; mt < 4; mt++)
#pragma unroll
    for (int nt = 0; nt < 4; nt++) acc[mt][nt] = (f32x4){0.f, 0.f, 0.f, 0.f};

  for (int k0 = 0; k0 < K; k0 += 64) {
    __syncthreads();
#pragma unroll
    for (int u = 0; u < 4; u++) {
      int t = wave + 4 * u;
      load_lds16(Ab[u] + k0, (char*)As + t * 1024);
      load_lds16(Bb[u] + k0, (char*)Bs + t * 1024);
    }
    __syncthreads();
#pragma unroll
    for (int kk = 0; kk < 2; kk++) {
      bf16x8 af[4], bfr[4];
#pragma unroll
      for (int mt = 0; mt < 4; mt++) {
        int r = wm + mt * 16 + l16;
        af[mt] = *(const bf16x8*)((const char*)As + r * 128 + (((kk * 4 + quad) ^ (r & 7)) << 4));
      }
#pragma unroll
      for (int nt = 0; nt < 4; nt++) {
        int r = wn + nt * 16 + l16;
        bfr[nt] = *(const bf16x8*)((const char*)Bs + r * 128 + (((kk * 4 + quad) ^ (r & 7)) << 4));
      }
#pragma unroll
      for (int mt = 0; mt < 4; mt++)
#pragma unroll
        for (int nt = 0; nt < 4; nt++)
          acc[mt][nt] = __builtin_amdgcn_mfma_f32_16x16x32_bf16(af[mt], bfr[nt], acc[mt][nt], 0, 0, 0);
    }
  }

#pragma unroll
  for (int mt = 0; mt < 4; mt++)
#pragma unroll
    for (int nt = 0; nt < 4; nt++)
#pragma unroll
      for (int r = 0; r < 4; r++) {
        int rr = m0 + wm + mt * 16 + quad * 4 + r;
        int cc = n0 + wn + nt * 16 + l16;
        if (c_fp32) ((float*)Cout)[(size_t)rr * N + cc] = acc[mt][nt][r];
        else        ((bf16*)Cout)[(size_t)rr * N + cc] = (bf16)acc[mt][nt][r];
      }
}

// ---------------- 128-tile GEMM + fused RoPE epilogue (kept for K projection, N=1024) ----
__global__ __launch_bounds__(256) void gemm_rope_kernel(const bf16* __restrict__ A,
                                                        const bf16* __restrict__ Bm,
                                                        bf16* __restrict__ Out,
                                                        int N, int K,
                                                        const float* __restrict__ cosT,
                                                        const float* __restrict__ sinT,
                                                        float outscale) {
  __shared__ char smem[32768];
  bf16* As = (bf16*)smem;
  bf16* Bs = (bf16*)(smem + 16384);
  float* Ex = (float*)smem;   // 256*17 floats, aliases As/Bs after main loop
  int tid = threadIdx.x;
  int wave = tid >> 6, lane = tid & 63, quad = lane >> 4, l16 = lane & 15;
  int m0 = blockIdx.y * 128, n0 = blockIdx.x * 128;
  int wm = (wave >> 1) * 64, wn = (wave & 1) * 64;

  int srow = lane >> 3;
  int schunk = (lane & 7) ^ (srow & 7);
  const bf16* Ab[4];
  const bf16* Bb[4];
#pragma unroll
  for (int u = 0; u < 4; u++) {
    int t = wave + 4 * u;
    Ab[u] = A  + (size_t)(m0 + 8 * t + srow) * K + schunk * 8;
    Bb[u] = Bm + (size_t)(n0 + 8 * t + srow) * K + schunk * 8;
  }

  f32x4 acc[4][4];
#pragma unroll
  for (int mt = 0; mt < 4; mt++)
#pragma unroll
    for (int nt = 0; nt < 4; nt++) acc[mt][nt] = (f32x4){0.f, 0.f, 0.f, 0.f};

  for (int k0 = 0; k0 < K; k0 += 64) {
    __syncthreads();
#pragma unroll
    for (int u = 0; u < 4; u++) {
      int t = wave + 4 * u;
      load_lds16(Ab[u] + k0, (char*)As + t * 1024);
      load_lds16(Bb[u] + k0, (char*)Bs + t * 1024);
    }
    __syncthreads();
#pragma unroll
    for (int kk = 0; kk < 2; kk++) {
      bf16x8 af[4], bfr[4];
#pragma unroll
      for (int mt = 0; mt < 4; mt++) {
        int r = wm + mt * 16 + l16;
        af[mt] = *(const bf16x8*)((const char*)As + r * 128 + (((kk * 4 + quad) ^ (r & 7)) << 4));
      }
#pragma unroll
      for (int nt = 0; nt < 4; nt++) {
        int r = wn + nt * 16 + l16;
        bfr[nt] = *(const bf16x8*)((const char*)Bs + r * 128 + (((kk * 4 + quad) ^ (r & 7)) << 4));
      }
#pragma unroll
      for (int mt = 0; mt < 4; mt++)
#pragma unroll
        for (int nt = 0; nt < 4; nt++)
          acc[mt][nt] = __builtin_amdgcn_mfma_f32_16x16x32_bf16(af[mt], bfr[nt], acc[mt][nt], 0, 0, 0);
    }
  }

  int myb = tid * 17;
  int pb = (tid ^ 64) * 17;    // partner: other 64-col half, same lane/regs
#pragma unroll
  for (int mt = 0; mt < 4; mt++) {
    __syncthreads();
#pragma unroll
    for (int nt = 0; nt < 4; nt++)
#pragma unroll
      for (int r = 0; r < 4; r++)
        Ex[myb + nt * 4 + r] = acc[mt][nt][r];
    __syncthreads();
    int rowb = m0 + wm + mt * 16 + quad * 4;
#pragma unroll
    for (int nt = 0; nt < 4; nt++) {
      int cc = n0 + wn + nt * 16 + l16;
      int d = cc & 127;
#pragma unroll
      for (int r = 0; r < 4; r++) {
        int row = rowb + r;
        int t = row & (S_ - 1);
        float self = acc[mt][nt][r];
        float other = Ex[pb + nt * 4 + r];
        float c = cosT[t * 128 + d], s = sinT[t * 128 + d];
        float o = (d < 64) ? (self * c - other * s) : (self * c + other * s);
        Out[(size_t)row * N + cc] = (bf16)(o * outscale);
      }
    }
  }
}

// ---------------- 256-tile 8-phase GEMM (T1+T2+T3+T4+T5), optional fused RoPE ---------
template<int FUSE_ROPE, int C_FP32>
__global__ __launch_bounds__(512, 2) void gemm256_kernel(const bf16* __restrict__ A,
                                                         const bf16* __restrict__ Bm,
                                                         void* __restrict__ Cout,
                                                         int N, int K,
                                                         const float* __restrict__ cosT,
                                                         const float* __restrict__ sinT,
                                                         float outscale) {
  __shared__ char smem[131072];
  const int tid = threadIdx.x;
  const int wave = tid >> 6, lane = tid & 63, quad = lane >> 4, l16 = lane & 15;
  const int wm = (wave >> 2) * 128, wn = (wave & 3) * 64;

  // XCD-aware bijective swizzle (grid is 16x16=256, 256%8==0)
  int bid = blockIdx.y * gridDim.x + blockIdx.x;
  int cpx = (gridDim.x * gridDim.y) >> 3;
  int wgid = (bid & 7) * cpx + (bid >> 3);
  int m0 = (wgid / gridDim.x) * 256;
  int n0 = (wgid % gridDim.x) * 256;

  const int srow = wave * 16 + (lane >> 2);
  const int sc = (lane & 3) ^ ((lane >> 2) & 3) ^ quad;
  const bf16* aS0 = A  + (size_t)(m0 + srow) * K + sc * 8;
  const bf16* aS1 = A  + (size_t)(m0 + 128 + srow) * K + sc * 8;
  const bf16* bS0 = Bm + (size_t)(n0 + srow) * K + sc * 8;
  const bf16* bS1 = Bm + (size_t)(n0 + 128 + srow) * K + sc * 8;
  const int wl = wave * 1024;

  const int rslot = ((quad ^ (l16 & 3) ^ ((l16 >> 2) & 3)) << 4);
  const int aoff = (wm + l16) * 64 + rslot;
  const int boff = (wn + l16) * 64 + rslot;

  f32x4 acc[8][4];
#pragma unroll
  for (int mt = 0; mt < 8; mt++)
#pragma unroll
    for (int nt = 0; nt < 4; nt++) acc[mt][nt] = (f32x4){0.f, 0.f, 0.f, 0.f};

  // prologue: stage all 4 halves of tile 0 into buf 0, drain once
  load_lds16(aS0,      smem +     0 + wl); load_lds16(aS1,      smem +  8192 + wl);
  load_lds16(bS0,      smem + 32768 + wl); load_lds16(bS1,      smem + 40960 + wl);
  load_lds16(aS0 + 32, smem + 16384 + wl); load_lds16(aS1 + 32, smem + 24576 + wl);
  load_lds16(bS0 + 32, smem + 49152 + wl); load_lds16(bS1 + 32, smem + 57344 + wl);
  asm volatile("s_waitcnt vmcnt(0)" ::: "memory");
  __builtin_amdgcn_s_barrier();

  const int NT = K >> 6;
  for (int t = 0; t < NT; ++t) {
    const char* base = smem + (t & 1) * 65536;
    char* nb = smem + ((t & 1) ^ 1) * 65536;
    const int off = (t + 1) << 6;      // next K-tile, in bf16 elements
    const bool more = (t + 1) < NT;
    bf16x8 afA[4], afB[4], bfr[4];

    // ---- phase 0: kk=0, rows wm..wm+63 ----
#pragma unroll
    for (int i = 0; i < 4; i++) afA[i] = *(const bf16x8*)(base + aoff + i * 1024);
#pragma unroll
    for (int i = 0; i < 4; i++) bfr[i] = *(const bf16x8*)(base + 32768 + boff + i * 1024);
    if (more) { load_lds16(aS0 + off, nb + wl); load_lds16(aS1 + off, nb + 8192 + wl); }
    __builtin_amdgcn_s_barrier();
    __builtin_amdgcn_s_setprio(1);
#pragma unroll
    for (int mt = 0; mt < 4; mt++)
#pragma unroll
      for (int nt = 0; nt < 4; nt++)
        acc[mt][nt] = __builtin_amdgcn_mfma_f32_16x16x32_bf16(afA[mt], bfr[nt], acc[mt][nt], 0, 0, 0);
    __builtin_amdgcn_s_setprio(0);
    __builtin_amdgcn_s_barrier();

    // ---- phase 1: kk=0, rows wm+64..wm+127; checkpoint: need k1 halves of tile t ----
#pragma unroll
    for (int i = 0; i < 4; i++) afB[i] = *(const bf16x8*)(base + aoff + (i + 4) * 1024);
    if (more) { load_lds16(bS0 + off, nb + 32768 + wl); load_lds16(bS1 + off, nb + 40960 + wl); }
    if (t == NT - 1) asm volatile("s_waitcnt vmcnt(0)" ::: "memory");   // epilogue drain
    else             asm volatile("s_waitcnt vmcnt(4)" ::: "memory");   // oldest 4 = k1(t)
    __builtin_amdgcn_s_barrier();
    __builtin_amdgcn_s_setprio(1);
#pragma unroll
    for (int mt = 0; mt < 4; mt++)
#pragma unroll
      for (int nt = 0; nt < 4; nt++)
        acc[mt + 4][nt] = __builtin_amdgcn_mfma_f32_16x16x32_bf16(afB[mt], bfr[nt], acc[mt + 4][nt], 0, 0, 0);
    __builtin_amdgcn_s_setprio(0);
    __builtin_amdgcn_s_barrier();

    // ---- phase 2: kk=1, rows wm..wm+63 ----
#pragma unroll
    for (int i = 0; i < 4; i++) afA[i] = *(const bf16x8*)(base + 16384 + aoff + i * 1024);
#pragma unroll
    for (int i = 0; i < 4; i++) bfr[i] = *(const bf16x8*)(base + 49152 + boff + i * 1024);
    if (more) { load_lds16(aS0 + off + 32, nb + 16384 + wl); load_lds16(aS1 + off + 32, nb + 24576 + wl); }
    __builtin_amdgcn_s_barrier();
    __builtin_amdgcn_s_setprio(1);
#pragma unroll
    for (int mt = 0; mt < 4; mt++)
#pragma unroll
      for (int nt = 0; nt < 4; nt++)
        acc[mt][nt] = __builtin_amdgcn_mfma_f32_16x16x32_bf16(afA[mt], bfr[nt], acc[mt][nt], 0, 0, 0);
    __builtin_amdgcn_s_setprio(0);
    __builtin_amdgcn_s_barrier();

    // ---- phase 3: kk=1, rows wm+64..wm+127; checkpoint: need k0 halves of tile t+1 ----
#pragma unroll
    for (int i = 0; i < 4; i++) afB[i] = *(const bf16x8*)(base + 16384 + aoff + (i + 4) * 1024);
    if (more) {
      load_lds16(bS0 + off + 32, nb + 49152 + wl); load_lds16(bS1 + off + 32, nb + 57344 + wl);
      asm volatile("s_waitcnt vmcnt(4)" ::: "memory");   // oldest 4 = k0(t+1)
    }
    __builtin_amdgcn_s_barrier();
    __builtin_amdgcn_s_setprio(1);
#pragma unroll
    for (int mt = 0; mt < 4; mt++)
#pragma unroll
      for (int nt = 0; nt < 4; nt++)
        acc[mt + 4][nt] = __builtin_amdgcn_mfma_f32_16x16x32_bf16(afB[mt], bfr[nt], acc[mt + 4][nt], 0, 0, 0);
    __builtin_amdgcn_s_setprio(0);
    __builtin_amdgcn_s_barrier();
  }

  if (FUSE_ROPE) {
    float* Ex = (float*)smem;      // 512*17 floats = 34816 B, aliases tile buffers
    int myb = tid * 17;
    int pb = (tid ^ 64) * 17;      // partner owns cc^64 (wave bit0 flips), same lane/regs
#pragma unroll
    for (int mt = 0; mt < 8; mt++) {
      __syncthreads();
#pragma unroll
      for (int nt = 0; nt < 4; nt++)
#pragma unroll
        for (int r = 0; r < 4; r++)
          Ex[myb + nt * 4 + r] = acc[mt][nt][r];
      __syncthreads();
      int rowb = m0 + wm + mt * 16 + quad * 4;
#pragma unroll
      for (int nt = 0; nt < 4; nt++) {
        int cc = n0 + wn + nt * 16 + l16;
        int d = cc & 127;
#pragma unroll
        for (int r = 0; r < 4; r++) {
          int row = rowb + r;
          int tp = row & (S_ - 1);
          float self = acc[mt][nt][r];
          float other = Ex[pb + nt * 4 + r];
          float c = cosT[tp * 128 + d], s = sinT[tp * 128 + d];
          float o = (d < 64) ? (self * c - other * s) : (self * c + other * s);
          ((bf16*)Cout)[(size_t)row * N + cc] = (bf16)(o * outscale);
        }
      }
    }
  } else {
#pragma unroll
    for (int mt = 0; mt < 8; mt++)
#pragma unroll
      for (int nt = 0; nt < 4; nt++)
#pragma unroll
        for (int r = 0; r < 4; r++) {
          int rr = m0 + wm + mt * 16 + quad * 4 + r;
          int cc = n0 + wn + nt * 16 + l16;
          if (C_FP32) ((float*)Cout)[(size_t)rr * N + cc] = acc[mt][nt][r];
          else        ((bf16*)Cout)[(size_t)rr * N + cc] = (bf16)acc[mt][nt][r];
        }
  }
}

// ---------------- fused causal GQA attention -----------------------------
// grid (8, NH, B), 512 threads = 8 waves; wave owns 16 Q rows; paired q-tiles
// (qt, 15-qt) -> uniform 34 j-iterations. K double-buffered + pipelined,
// V staged behind the QK^T/softmax phase. DPP reductions, exp2-domain softmax
// (Q pre-scaled by 1/sqrt(d)*log2(e) in rope epilogue).
// v2: T13 defer-max (skip rescale unless wave max grew > 8 in log2 => P <= 256),
//     deferred denominator (per-lane psum, single red16_sum in epilogue),
//     P-store swizzle sigma(m)=2*(m>>2) (full-quad bank spread; was 4-way conflicted),
//     wave-uniform skip of fully-masked diagonal+64 tiles.
__global__ __launch_bounds__(512, 4) void attn_kernel(const bf16* __restrict__ Qm,
                                                      const bf16* __restrict__ Km,
                                                      const bf16* __restrict__ VtG,
                                                      bf16* __restrict__ Cm) {
  __shared__ char sK[32768];   // 2 x 16KB: addr(key,dc16)=key*256 + ((dc^(key&7))<<4)
  __shared__ char sV[16384];   // addr(d,kc8)=d*128 + ((kc^(d&7))<<4)
  __shared__ char sP[16384];   // 8 waves x 2KB: addr(m,kc8)=m*128 + ((kc ^ (2*(m>>2)))<<4)
  int tid = threadIdx.x;
  int wave = tid >> 6, lane = tid & 63, quad = lane >> 4, l16 = lane & 15;
  int h = blockIdx.y, b = blockIdx.z;
  int kvh = h >> 2;

  // staging pointers (qt-independent); each wave stages 2x1KB of K and of V
  const bf16* Kb[2];
  const bf16* Vb[2];
  {
    int r4 = lane >> 4, c16 = lane & 15;
    int r8 = lane >> 3, c8 = lane & 7;
#pragma unroll
    for (int u = 0; u < 2; u++) {
      int t = wave * 2 + u;
      int key = 4 * t + r4;
      int kc = c16 ^ (key & 7);
      Kb[u] = Km + (size_t)(b * S_ + key) * (NKV_ * HD_) + kvh * HD_ + kc * 8;
      int d = 8 * t + r8;
      int vc = c8 ^ (d & 7);
      Vb[u] = VtG + (size_t)(kvh * HD_ + d) * T_ + (size_t)b * S_ + vc * 8;
    }
  }

  for (int pass = 0; pass < 2; pass++) {
    int qt = pass ? ((S_ / 128 - 1) - (int)blockIdx.x) : (int)blockIdx.x;
    int q0 = qt * 128;
    int jend = q0 + 128;

    // pre-stage K tile j0=0 into buffer 0 (safe: pass N-1 readers are past
    // their last barrier before any wave gets here)
#pragma unroll
    for (int u = 0; u < 2; u++)
      load_lds16(Kb[u], sK + (wave * 2 + u) * 1024);

    // Q fragments: A[m=l16][k=quad*8+j]
    bf16x8 aQ[4];
    {
      int row = q0 + wave * 16 + l16;
      const bf16* qb = Qm + (size_t)(b * S_ + row) * (NH_ * HD_) + h * HD_;
#pragma unroll
      for (int kt = 0; kt < 4; kt++)
        aQ[kt] = *(const bf16x8*)(qb + kt * 32 + quad * 8);
    }

    float mcur[4], psum[4];
    f32x4 O[8];
#pragma unroll
    for (int r = 0; r < 4; r++) { mcur[r] = -1e30f; psum[r] = 0.f; }
#pragma unroll
    for (int n = 0; n < 8; n++) O[n] = (f32x4){0.f, 0.f, 0.f, 0.f};

    for (int j0 = 0; j0 < jend; j0 += 64) {
      int cur = (j0 >> 6) & 1;
      __syncthreads();   // K(cur) staged (issued one full iteration ago)
      // issue next K tile + this iteration's V tile (both land during compute)
      if (j0 + 64 < jend) {
#pragma unroll
        for (int u = 0; u < 2; u++)
          load_lds16(Kb[u] + (size_t)(j0 + 64) * (NKV_ * HD_),
                     sK + (1 - cur) * 16384 + (wave * 2 + u) * 1024);
      }
#pragma unroll
      for (int u = 0; u < 2; u++)
        load_lds16(Vb[u] + j0, sV + (wave * 2 + u) * 1024);

      // wave-uniform: is this tile entirely above the diagonal for all 16 rows?
      bool active = (j0 <= q0 + wave * 16 + 15);

      if (active) {
        // QK^T: 16 rows x 64 keys per wave
        const char* Kc = sK + cur * 16384;
        f32x4 sc[4];
#pragma unroll
        for (int nt = 0; nt < 4; nt++) sc[nt] = (f32x4){0.f, 0.f, 0.f, 0.f};
#pragma unroll
        for (int kt = 0; kt < 4; kt++) {
          bf16x8 bk[4];
#pragma unroll
          for (int nt = 0; nt < 4; nt++) {
            int key = nt * 16 + l16;
            bk[nt] = *(const bf16x8*)(Kc + key * 256 + (((kt * 4 + quad) ^ (key & 7)) << 4));
          }
#pragma unroll
          for (int nt = 0; nt < 4; nt++)
            sc[nt] = __builtin_amdgcn_mfma_f32_16x16x32_bf16(aQ[kt], bk[nt], sc[nt], 0, 0, 0);
        }

        // causal mask (wave-uniform skip for fully-visible tiles)
        int rowb = q0 + wave * 16 + quad * 4;
        if (j0 + 63 > q0 + wave * 16) {
#pragma unroll
          for (int nt = 0; nt < 4; nt++) {
            int col = j0 + nt * 16 + l16;
#pragma unroll
            for (int r = 0; r < 4; r++)
              if (col > rowb + r) sc[nt][r] = -1e9f;
          }
        }

        // defer-max online softmax: rescale only when wave max grows > 8 (log2)
        float vmax[4];
#pragma unroll
        for (int r = 0; r < 4; r++)
          vmax[r] = fmaxf(fmaxf(sc[0][r], sc[1][r]), fmaxf(sc[2][r], sc[3][r]));
        int nd = 0;
#pragma unroll
        for (int r = 0; r < 4; r++) nd |= (vmax[r] > mcur[r] + 8.f) ? 1 : 0;
        if (__any(nd)) {
          float al[4];
#pragma unroll
          for (int r = 0; r < 4; r++) {
            float rm = red16_max(vmax[r]);
            float mnew = fmaxf(mcur[r], rm);
            al[r] = exp2f(mcur[r] - mnew);
            mcur[r] = mnew;
            psum[r] *= al[r];
          }
#pragma unroll
          for (int n = 0; n < 8; n++)
#pragma unroll
            for (int r = 0; r < 4; r++) O[n][r] *= al[r];
        }
#pragma unroll
        for (int nt = 0; nt < 4; nt++)
#pragma unroll
          for (int r = 0; r < 4; r++)
            sc[nt][r] = exp2f(sc[nt][r] - mcur[r]);
#pragma unroll
        for (int r = 0; r < 4; r++)
          psum[r] += (sc[0][r] + sc[1][r]) + (sc[2][r] + sc[3][r]);

        // P -> LDS (C-layout -> A-frag layout), wave-private region
        // sigma(m) = 2*((m>>2)&3): write groups (quad, l16>>3) hit 8 distinct 16B
        // slots; rows are bank-neutral (128B stride) -> conflict-free
        char* Pw = sP + wave * 2048;
#pragma unroll
        for (int nt = 0; nt < 4; nt++) {
          int key = nt * 16 + l16;
#pragma unroll
          for (int r = 0; r < 4; r++) {
            int m = quad * 4 + r;
            *(bf16*)(Pw + m * 128 + ((((key >> 3) ^ (2 * quad)) & 7) << 4) + (key & 7) * 2) =
                (bf16)sc[nt][r];
          }
        }
      }

      __syncthreads();   // V(cur) staged (landed during QK^T+softmax); P visible intra-wave

      if (active) {
        // ctx += P * V
        char* Pw = sP + wave * 2048;
#pragma unroll
        for (int kt = 0; kt < 2; kt++) {
          bf16x8 ap = *(const bf16x8*)(Pw + l16 * 128 +
                      ((((kt * 4 + quad) ^ (2 * ((l16 >> 2) & 3))) & 7) << 4));
#pragma unroll
          for (int nt = 0; nt < 8; nt++) {
            int d = nt * 16 + l16;
            bf16x8 bv = *(const bf16x8*)(sV + d * 128 + (((kt * 4 + quad) ^ (d & 7)) << 4));
            O[nt] = __builtin_amdgcn_mfma_f32_16x16x32_bf16(ap, bv, O[nt], 0, 0, 0);
          }
        }
      }
    }

    // epilogue: single deferred denominator reduction, then scale
    float linv[4];
#pragma unroll
    for (int r = 0; r < 4; r++) linv[r] = 1.0f / red16_sum(psum[r]);
#pragma unroll
    for (int nt = 0; nt < 8; nt++)
#pragma unroll
      for (int r = 0; r < 4; r++) {
        int row = q0 + wave * 16 + quad * 4 + r;
        Cm[(size_t)(b * S_ + row) * (NH_ * HD_) + h * HD_ + nt * 16 + l16] =
            (bf16)(O[nt][r] * linv[r]);
      }
  }
}

extern "C" void kernel_launch(void* const* d_in, const int* in_sizes, int n_in,
                              void* d_out, int out_size, void* d_ws, size_t ws_size,
                              hipStream_t stream) {
  const float* hidden = (const float*)d_in[0];
  const float* cosT   = (const float*)d_in[1];
  const float* sinT   = (const float*)d_in[2];
  const int*   q_qw = (const int*)d_in[4];
  const float* q_sc = (const float*)d_in[5];
  const int*   k_qw = (const int*)d_in[6];
  const float* k_sc = (const float*)d_in[7];
  const int*   v_qw = (const int*)d_in[8];
  const float* v_sc = (const float*)d_in[9];
  const int*   o_qw = (const int*)d_in[10];
  const float* o_sc = (const float*)d_in[11];

  const size_t MB = 1024 * 1024;
  char* ws = (char*)d_ws;
  bf16* Xb  = (bf16*)(ws);             // 32MB  hidden bf16; later reused as ctx
  bf16* Wb  = (bf16*)(ws + 32 * MB);   // 32MB  current dequantized weight
  bf16* Qm  = (bf16*)(ws + 64 * MB);   // 32MB  [T][4096]
  bf16* Km  = (bf16*)(ws + 96 * MB);   // 8MB   [T][1024]
  bf16* VtG = (bf16*)(ws + 104 * MB);  // 8MB   [1024][T]  (V transposed)
  bf16* Cm  = Xb;

  cvt_bf16_kernel<<<(T_ * HID_ / 4 + 255) / 256, 256, 0, stream>>>(hidden, Xb, T_ * HID_ / 4);

  // Q pre-scale: 1/sqrt(128) * log2(e)  (softmax runs in exp2 domain)
  const float qscale = (float)(0.08838834764831845 * 1.4426950408889634);

  // Q projection + fused rope (256-tile 8-phase; grid 16x16 = 256 blocks = 1/CU)
  dequant_kernel<<<(4096 * 512 + 255) / 256, 256, 0, stream>>>(q_qw, q_sc, Wb, 4096, 4096);
  gemm256_kernel<1, 0><<<dim3(16, 16), 512, 0, stream>>>(Xb, Wb, Qm, 4096, 4096,
                                                         cosT, sinT, qscale);

  // K projection + fused rope (N=1024: keep 128-tile, 256 blocks)
  dequant_kernel<<<(1024 * 512 + 255) / 256, 256, 0, stream>>>(k_qw, k_sc, Wb, 1024, 4096);
  gemm_rope_kernel<<<dim3(8, 32), 256, 0, stream>>>(Xb, Wb, Km, 1024, 4096, cosT, sinT, 1.0f);

  // V projection, written TRANSPOSED: V^T[1024][T] = Wv * X^T (keep 128-tile)
  dequant_kernel<<<(1024 * 512 + 255) / 256, 256, 0, stream>>>(v_qw, v_sc, Wb, 1024, 4096);
  gemm_bt_kernel<<<dim3(32, 8), 256, 0, stream>>>(Wb, Xb, VtG, 4096, 4096, 0);

  // attention (8 waves/block, paired q-tiles; writes Cm = Xb region)
  attn_kernel<<<dim3(8, NH_, B_), 512, 0, stream>>>(Qm, Km, VtG, Cm);

  // output projection -> fp32 d_out (256-tile 8-phase)
  dequant_kernel<<<(4096 * 512 + 255) / 256, 256, 0, stream>>>(o_qw, o_sc, Wb, 4096, 4096);
  gemm256_kernel<0, 1><<<dim3(16, 16), 512, 0, stream>>>(Cm, Wb, d_out, 4096, 4096,
                                                         nullptr, nullptr, 1.0f);
}